// Round 2
// baseline (50443.878 us; speedup 1.0000x reference)
//
#include <hip/hip_runtime.h>
#include <math.h>

// Problem constants (from reference): B,T,D,H,DS
#define BB 64
#define TT 512
#define DD 128
#define HH 512
#define DSZ 32
#define G4 (4 * HH)   // 2048

// ---------------------------------------------------------------------------
// LSTM step kernel: one launch per timestep t.
// Grid: 128 blocks x 256 threads.
//   Block bid owns j in [bid*4, bid*4+4) for ALL 4 gates -> 16 z-columns,
//   for ALL 64 batches.  => W_rec read exactly once per step across grid.
// Thread tid: b = tid>>2 (0..63), g = tid&3 (gate). Each thread accumulates
//   4 consecutive z-columns (float4) for (batch b, gate g).
// After the K loops, gates are exchanged through LDS so thread (b,jj) has
//   i,f,g,o for one (b,j) and performs the c/h update.
// ---------------------------------------------------------------------------
__global__ __launch_bounds__(256) void lstm_step(
    const float* __restrict__ x,     // [B,T,D]
    const float* __restrict__ kern,  // [D,4H]
    const float* __restrict__ rker,  // [H,4H]
    const float* __restrict__ bias,  // [4H]
    float* __restrict__ seq,         // [B,T,H]  (h for every t)
    float* __restrict__ cbuf,        // [B,H]
    int t)
{
    __shared__ float sh[64][65];    // h chunk [batch][k], +1 pad: bank = (b+k)%32
    __shared__ float sx[64][129];   // x row   [batch][d], +1 pad
    __shared__ float sex[256][4];   // gate exchange

    const int tid = threadIdx.x;
    const int b  = tid >> 2;        // 0..63
    const int g  = tid & 3;         // 0..3 (gate i,f,g,o)
    const int j0 = blockIdx.x * 4;  // 0..508
    const int col = g * HH + j0;    // column into 4H

    float4 acc;
    acc.x = bias[col + 0];
    acc.y = bias[col + 1];
    acc.z = bias[col + 2];
    acc.w = bias[col + 3];

    // ---- stage x[:, t, :]  (64 x 128 floats) ----
    for (int i = tid; i < 64 * 128; i += 256) {
        int bb = i >> 7, dd = i & 127;
        sx[bb][dd] = x[(bb * TT + t) * DD + dd];
    }
    __syncthreads();

    // ---- input projection: acc += x[b,t,:] @ kern[:, col..col+3] ----
    {
        const float* kp = kern + col;
        #pragma unroll 8
        for (int k = 0; k < DD; ++k) {
            float xv = sx[b][k];
            float4 w = *(const float4*)(kp + (size_t)k * G4);
            acc.x += xv * w.x; acc.y += xv * w.y;
            acc.z += xv * w.z; acc.w += xv * w.w;
        }
    }

    // ---- recurrent projection: acc += h_prev[b,:] @ rker[:, col..col+3] ----
    if (t > 0) {
        const float* rp = rker + col;
        for (int k0 = 0; k0 < HH; k0 += 64) {
            __syncthreads();  // protect previous sh chunk
            for (int i = tid; i < 64 * 64; i += 256) {
                int bb = i >> 6, kk = i & 63;
                sh[bb][kk] = seq[((size_t)bb * TT + (t - 1)) * HH + k0 + kk];
            }
            __syncthreads();
            #pragma unroll 8
            for (int kk = 0; kk < 64; ++kk) {
                float hv = sh[b][kk];
                float4 w = *(const float4*)(rp + (size_t)(k0 + kk) * G4);
                acc.x += hv * w.x; acc.y += hv * w.y;
                acc.z += hv * w.z; acc.w += hv * w.w;
            }
        }
    }

    // ---- exchange gates via LDS ----
    sex[tid][0] = acc.x;
    sex[tid][1] = acc.y;
    sex[tid][2] = acc.z;
    sex[tid][3] = acc.w;
    __syncthreads();

    // repartition: thread -> (b2, jj); reads i,f,g,o for (b2, j0+jj)
    const int b2 = tid >> 2;
    const int jj = tid & 3;
    float zi = sex[b2 * 4 + 0][jj];
    float zf = sex[b2 * 4 + 1][jj];
    float zg = sex[b2 * 4 + 2][jj];
    float zo = sex[b2 * 4 + 3][jj];

    float iv = 1.f / (1.f + expf(-zi));
    float fv = 1.f / (1.f + expf(-zf));
    float gv = tanhf(zg);
    float ov = 1.f / (1.f + expf(-zo));

    const int j = j0 + jj;
    float cprev = (t == 0) ? 0.f : cbuf[b2 * HH + j];
    float c = fv * cprev + iv * gv;
    float h = ov * tanhf(c);

    cbuf[b2 * HH + j] = c;
    seq[((size_t)b2 * TT + t) * HH + j] = h;
}

// ---------------------------------------------------------------------------
// Dense(32, tanh) over all timesteps: out[row, ds] = tanh(seq[row,:] @ dw + db)
// Block: 8 rows x 32 ds = 256 threads. Grid: 32768/8 = 4096 blocks.
// ---------------------------------------------------------------------------
__global__ __launch_bounds__(256) void dense_kernel(
    const float* __restrict__ seq,   // [B*T, H]
    const float* __restrict__ dw,    // [H, DS]
    const float* __restrict__ db,    // [DS]
    float* __restrict__ out)         // [B*T, DS]
{
    const int tid = threadIdx.x;
    const int ds = tid & 31;
    const int r8 = tid >> 5;
    const size_t row = (size_t)blockIdx.x * 8 + r8;
    const float* srow = seq + row * HH;
    float acc = db[ds];
    #pragma unroll 8
    for (int k = 0; k < HH; ++k)
        acc += srow[k] * dw[k * DSZ + ds];
    out[row * DSZ + ds] = tanhf(acc);
}

// ---------------------------------------------------------------------------
// Final h (= seq[:,T-1,:]) and c into the tail of d_out.
// ---------------------------------------------------------------------------
__global__ __launch_bounds__(256) void finalize(
    const float* __restrict__ seq, const float* __restrict__ cbuf,
    float* __restrict__ out)
{
    int i = blockIdx.x * 256 + threadIdx.x;  // 0..32767
    if (i < BB * HH) {
        int b = i / HH, j = i % HH;
        out[(size_t)BB * TT * DSZ + i] = seq[((size_t)b * TT + (TT - 1)) * HH + j];
        out[(size_t)BB * TT * DSZ + BB * HH + i] = cbuf[i];
    }
}

extern "C" void kernel_launch(void* const* d_in, const int* in_sizes, int n_in,
                              void* d_out, int out_size, void* d_ws, size_t ws_size,
                              hipStream_t stream) {
    const float* x    = (const float*)d_in[0];  // [B,T,D]
    const float* kern = (const float*)d_in[1];  // [D,4H]
    const float* rker = (const float*)d_in[2];  // [H,4H]
    const float* bias = (const float*)d_in[3];  // [4H]
    const float* dw   = (const float*)d_in[4];  // [H,DS]
    const float* db   = (const float*)d_in[5];  // [DS]
    float* out = (float*)d_out;

    float* seq  = (float*)d_ws;                      // B*T*H floats = 64 MB
    float* cbuf = seq + (size_t)BB * TT * HH;        // B*H floats

    for (int t = 0; t < TT; ++t)
        lstm_step<<<128, 256, 0, stream>>>(x, kern, rker, bias, seq, cbuf, t);

    dense_kernel<<<4096, 256, 0, stream>>>(seq, dw, db, out);
    finalize<<<128, 256, 0, stream>>>(seq, cbuf, out);
}

// Round 3
// 8157.862 us; speedup vs baseline: 6.1835x; 6.1835x over previous
//
#include <hip/hip_runtime.h>
#include <math.h>

// B=64, T=512, D=128, H=512, DS=32
#define BB 64
#define TT 512
#define DD 128
#define HH 512
#define DSZ 32
#define NBLK 64          // persistent blocks; 8 hidden units (32 z-cols) each
#define NTHR 512         // 8 waves: 4 m-tiles x 2 n-tiles of 16x16

typedef _Float16 f16;
typedef f16 f16x8 __attribute__((ext_vector_type(8)));
typedef float f32x4 __attribute__((ext_vector_type(4)));

// LDS strides (f16 units). Row stride 520 = 512+8: 1040B rows keep 16B align
// and spread A/B-frag b128 reads evenly over bank groups ((b+kb)%8 balanced).
#define SW 520
#define SK 136
// LDS carve (bytes): Wt[32][520] 33280 | kt[32][136] 8704 | h[64][520] 66560
//                    x[64][136] 17408 | zx[64][33] f32 8448  => total 134400
#define LDS_BYTES 134400

__global__ __launch_bounds__(NTHR, 1) void lstm_persistent(
    const float* __restrict__ x,     // [B,T,D]
    const float* __restrict__ kern,  // [D,4H]
    const float* __restrict__ rker,  // [H,4H]
    const float* __restrict__ bias,  // [4H]
    f16* __restrict__ seq16,         // [B,T,H] f16 (ws)
    f16* __restrict__ h16g,          // [B,H]   f16 (ws) current h
    unsigned int* __restrict__ flags,// [NBLK] (ws, poisoned 0xAA.. each run)
    float* __restrict__ out)         // final h,c tail of d_out
{
    extern __shared__ char smem[];
    f16*   Wt   = (f16*)smem;                 // [32 zc][SW]  (W^T, f16)
    f16*   kt   = Wt + 32 * SW;               // [32 zc][SK]
    f16*   hlds = kt + 32 * SK;               // [64 b][SW]
    f16*   xlds = hlds + 64 * SW;             // [64 b][SK]
    float* zx   = (float*)(xlds + 64 * SK);   // [64 b][33]

    const int tid  = threadIdx.x;
    const int bid  = blockIdx.x;
    const int jbase = bid * 8;                // hidden units [jbase, jbase+8)

    // ---- one-time: W^T and kern^T slices -> LDS f16 ----
    // block column c in 0..31  <->  global z-col  (c>>3)*HH + jbase + (c&7)
    for (int idx = tid; idx < 32 * HH; idx += NTHR) {
        int c = idx & 31, k = idx >> 5;
        float v = rker[(size_t)k * (4 * HH) + (c >> 3) * HH + jbase + (c & 7)];
        Wt[c * SW + k] = (f16)v;
    }
    for (int idx = tid; idx < 32 * DD; idx += NTHR) {
        int c = idx & 31, k = idx >> 5;
        float v = kern[(size_t)k * (4 * HH) + (c >> 3) * HH + jbase + (c & 7)];
        kt[c * SK + k] = (f16)v;
    }

    // gate-phase identity: thread -> (b, j)
    const int gb = tid >> 3;          // 0..63
    const int gj = tid & 7;           // 0..7
    float bias_r[4];
    #pragma unroll
    for (int g = 0; g < 4; ++g) bias_r[g] = bias[g * HH + jbase + gj];
    float creg = 0.f;

    // MFMA identity: 8 waves = 4 m-tiles x 2 n-tiles
    const int wave = tid >> 6, lane = tid & 63;
    const int mtile = wave & 3, ntile = wave >> 2;
    const int arow = mtile * 16 + (lane & 15);       // A row (batch)
    const int bcol = ntile * 16 + (lane & 15);       // B col (block z-col)
    const int kseg = (lane >> 4) * 8;                // k offset within K=32 step

    __syncthreads();

    for (int t = 0; t < TT; ++t) {
        // ---- stage x[:, t, :] -> f16 LDS ----
        for (int idx = tid; idx < BB * DD; idx += NTHR) {
            int b = idx >> 7, d = idx & 127;
            xlds[b * SK + d] = (f16)x[((size_t)b * TT + t) * DD + d];
        }
        __syncthreads();

        // ---- input projection via MFMA (K=128 -> 4 steps) ----
        f32x4 acc = {0.f, 0.f, 0.f, 0.f};
        #pragma unroll
        for (int ks = 0; ks < 4; ++ks) {
            f16x8 a = *(const f16x8*)(xlds + arow * SK + ks * 32 + kseg);
            f16x8 bf = *(const f16x8*)(kt + bcol * SK + ks * 32 + kseg);
            acc = __builtin_amdgcn_mfma_f32_16x16x32_f16(a, bf, acc, 0, 0, 0);
        }

        if (t > 0) {
            // ---- wait for all blocks to have published h(t-1) ----
            if (tid < NBLK) {
                while (__hip_atomic_load(&flags[tid], __ATOMIC_ACQUIRE,
                                         __HIP_MEMORY_SCOPE_AGENT) != (unsigned)t) {
                    __builtin_amdgcn_s_sleep(1);
                }
            }
            __syncthreads();
            // ---- stage h(t-1): 64KB, 16B units ----
            for (int u = tid; u < BB * (HH / 8); u += NTHR) {
                int b = u >> 6, kb = u & 63;
                *(int4*)(hlds + b * SW + kb * 8) =
                    *(const int4*)(h16g + b * HH + kb * 8);
            }
            __syncthreads();
            // ---- recurrent projection via MFMA (K=512 -> 16 steps) ----
            #pragma unroll 4
            for (int ks = 0; ks < 16; ++ks) {
                f16x8 a = *(const f16x8*)(hlds + arow * SW + ks * 32 + kseg);
                f16x8 bf = *(const f16x8*)(Wt + bcol * SW + ks * 32 + kseg);
                acc = __builtin_amdgcn_mfma_f32_16x16x32_f16(a, bf, acc, 0, 0, 0);
            }
        }

        // ---- exchange z via LDS: C/D map col=lane&15, row=(lane>>4)*4+r ----
        {
            int rb = mtile * 16 + (lane >> 4) * 4;
            #pragma unroll
            for (int r = 0; r < 4; ++r) zx[(rb + r) * 33 + bcol] = acc[r];
        }
        __syncthreads();

        // ---- gates: thread (gb, gj); z-cols c = g*8 + gj ----
        {
            float zi = zx[gb * 33 + 0 * 8 + gj] + bias_r[0];
            float zf = zx[gb * 33 + 1 * 8 + gj] + bias_r[1];
            float zg = zx[gb * 33 + 2 * 8 + gj] + bias_r[2];
            float zo = zx[gb * 33 + 3 * 8 + gj] + bias_r[3];
            float iv = 1.f / (1.f + expf(-zi));
            float fv = 1.f / (1.f + expf(-zf));
            float gv = tanhf(zg);
            float ov = 1.f / (1.f + expf(-zo));
            creg = fv * creg + iv * gv;
            float h = ov * tanhf(creg);
            f16 h16 = (f16)h;
            h16g[gb * HH + jbase + gj] = h16;
            seq16[((size_t)gb * TT + t) * HH + jbase + gj] = h16;
            if (t == TT - 1) {
                out[(size_t)BB * TT * DSZ + gb * HH + jbase + gj] = h;
                out[(size_t)BB * TT * DSZ + BB * HH + gb * HH + jbase + gj] = creg;
            }
        }
        __threadfence();
        __syncthreads();
        if (tid == 0)
            __hip_atomic_store(&flags[bid], (unsigned)(t + 1), __ATOMIC_RELEASE,
                               __HIP_MEMORY_SCOPE_AGENT);
    }
}

// ---------------------------------------------------------------------------
// Dense(32, tanh): out[row, ds] = tanh(seq16[row,:] @ dw + db)
// ---------------------------------------------------------------------------
__global__ __launch_bounds__(256) void dense_kernel(
    const f16* __restrict__ seq16,   // [B*T, H]
    const float* __restrict__ dw,    // [H, DS]
    const float* __restrict__ db,    // [DS]
    float* __restrict__ out)         // [B*T, DS]
{
    const int tid = threadIdx.x;
    const int ds = tid & 31;
    const int r8 = tid >> 5;
    const size_t row = (size_t)blockIdx.x * 8 + r8;
    const f16* srow = seq16 + row * HH;
    float acc = db[ds];
    #pragma unroll 8
    for (int k = 0; k < HH; ++k)
        acc += (float)srow[k] * dw[k * DSZ + ds];
    out[row * DSZ + ds] = tanhf(acc);
}

extern "C" void kernel_launch(void* const* d_in, const int* in_sizes, int n_in,
                              void* d_out, int out_size, void* d_ws, size_t ws_size,
                              hipStream_t stream) {
    const float* x    = (const float*)d_in[0];
    const float* kern = (const float*)d_in[1];
    const float* rker = (const float*)d_in[2];
    const float* bias = (const float*)d_in[3];
    const float* dw   = (const float*)d_in[4];
    const float* db   = (const float*)d_in[5];
    float* out = (float*)d_out;

    f16* seq16 = (f16*)d_ws;                                    // 33554432 B
    f16* h16g  = (f16*)((char*)d_ws + (size_t)33554432);        // 65536 B
    unsigned int* flags = (unsigned int*)((char*)d_ws + 33554432 + 65536);

    hipFuncSetAttribute((const void*)lstm_persistent,
                        hipFuncAttributeMaxDynamicSharedMemorySize, LDS_BYTES);

    lstm_persistent<<<NBLK, NTHR, LDS_BYTES, stream>>>(
        x, kern, rker, bias, seq16, h16g, flags, out);
    dense_kernel<<<4096, 256, 0, stream>>>(seq16, dw, db, out);
}

// Round 4
// 5289.571 us; speedup vs baseline: 9.5365x; 1.5423x over previous
//
#include <hip/hip_runtime.h>
#include <math.h>

// B=64, T=512, D=128, H=512, DS=32
#define BB 64
#define TT 512
#define DD 128
#define HH 512
#define DSZ 32
#define G4 (4 * HH)       // 2048
#define NBLK 64           // persistent blocks: 8 hidden units (32 z-cols) each
#define NTHR 512          // 8 waves: 4 m-tiles (batch) x 2 n-tiles (cols)
#define OUT_TAIL (BB * TT * DSZ)   // 1,048,576 floats

typedef _Float16 f16;
typedef f16  f16x8 __attribute__((ext_vector_type(8)));
typedef float f32x4 __attribute__((ext_vector_type(4)));

// ---------------------------------------------------------------------------
// Persistent LSTM. Block bid owns hidden units [bid*8, bid*8+8) => 32 z-cols.
// W_rec/kern fragments live in VGPRs (loaded once). h exchanged through
// global hbuf[2] (double-buffered, race-free) read directly as MFMA A-frags.
// LDS: only the 8.4KB z gate-exchange buffer.
// ---------------------------------------------------------------------------
__global__ __launch_bounds__(NTHR, 1) void lstm_persistent(
    const float* __restrict__ x,      // [B,T,D]
    const float* __restrict__ kern,   // [D,4H]
    const float* __restrict__ rker,   // [H,4H]
    const float* __restrict__ bias,   // [4H]
    f16* __restrict__ seq16,          // [T,B,H] f16 (ws)
    f16* __restrict__ hbuf,           // [2,B,H] f16 (ws)
    unsigned int* __restrict__ flags, // [NBLK]  (ws, 0xAA poison ok: != any t)
    float* __restrict__ out)
{
    __shared__ float zx[64 * 33];     // [batch][32 z-cols], stride 33

    const int tid = threadIdx.x;
    const int bid = blockIdx.x;
    const int jbase = bid * 8;

    const int wave = tid >> 6, lane = tid & 63;
    const int mtile = wave & 3;           // batch tile
    const int ntile = wave >> 2;          // col tile (0/1)
    const int arow = mtile * 16 + (lane & 15);   // batch row for A frags
    const int nc   = ntile * 16 + (lane & 15);   // block z-col 0..31
    const int kseg = (lane >> 4) * 8;            // k sub-offset
    const int gcol = (nc >> 3) * HH + jbase + (nc & 7);  // global z-col

    // ---- one-time: weight fragments -> VGPRs ----
    f16x8 wfrag[16];
    #pragma unroll
    for (int ks = 0; ks < 16; ++ks) {
        f16x8 w;
        #pragma unroll
        for (int j = 0; j < 8; ++j)
            w[j] = (f16)rker[(size_t)(ks * 32 + kseg + j) * G4 + gcol];
        wfrag[ks] = w;
    }
    f16x8 kfrag[4];
    #pragma unroll
    for (int ks = 0; ks < 4; ++ks) {
        f16x8 w;
        #pragma unroll
        for (int j = 0; j < 8; ++j)
            w[j] = (f16)kern[(size_t)(ks * 32 + kseg + j) * G4 + gcol];
        kfrag[ks] = w;
    }

    // gate-phase identity: thread -> (batch gb, unit gj)
    const int gb = tid >> 3, gj = tid & 7;
    float bias_r[4];
    #pragma unroll
    for (int g = 0; g < 4; ++g) bias_r[g] = bias[g * HH + jbase + gj];
    float creg = 0.f;

    const float* xrow = x + (size_t)arow * TT * DD;

    for (int t = 0; t < TT; ++t) {
        // ---- input projection (independent of recurrence; runs pre-poll) ----
        f32x4 acc = {0.f, 0.f, 0.f, 0.f};
        #pragma unroll
        for (int ks = 0; ks < 4; ++ks) {
            const float* p = xrow + t * DD + ks * 32 + kseg;
            float4 a = *(const float4*)p;
            float4 b = *(const float4*)(p + 4);
            f16x8 xa;
            xa[0] = (f16)a.x; xa[1] = (f16)a.y; xa[2] = (f16)a.z; xa[3] = (f16)a.w;
            xa[4] = (f16)b.x; xa[5] = (f16)b.y; xa[6] = (f16)b.z; xa[7] = (f16)b.w;
            acc = __builtin_amdgcn_mfma_f32_16x16x32_f16(xa, kfrag[ks], acc, 0, 0, 0);
        }

        if (t > 0) {
            // ---- wait for h(t-1) from all blocks ----
            if (tid < NBLK) {
                while (__hip_atomic_load(&flags[tid], __ATOMIC_ACQUIRE,
                                         __HIP_MEMORY_SCOPE_AGENT) != (unsigned)t) {
                    __builtin_amdgcn_s_sleep(1);
                }
            }
            __syncthreads();
            // ---- recurrent projection: A-frags straight from global hbuf ----
            const f16* hp = hbuf + ((t - 1) & 1) * (BB * HH)
                          + (size_t)arow * HH + kseg;
            #pragma unroll
            for (int ks = 0; ks < 16; ++ks) {
                f16x8 ha = *(const f16x8*)(hp + ks * 32);
                acc = __builtin_amdgcn_mfma_f32_16x16x32_f16(ha, wfrag[ks], acc, 0, 0, 0);
            }
        }

        // ---- z exchange: C/D map col=lane&15, row=(lane>>4)*4+r ----
        {
            const int rb = mtile * 16 + (lane >> 4) * 4;
            #pragma unroll
            for (int r = 0; r < 4; ++r) zx[(rb + r) * 33 + nc] = acc[r];
        }
        __syncthreads();

        // ---- gates ----
        float zi = zx[gb * 33 +  0 + gj] + bias_r[0];
        float zf = zx[gb * 33 +  8 + gj] + bias_r[1];
        float zg = zx[gb * 33 + 16 + gj] + bias_r[2];
        float zo = zx[gb * 33 + 24 + gj] + bias_r[3];
        float iv = 1.f / (1.f + expf(-zi));
        float fv = 1.f / (1.f + expf(-zf));
        float gv = tanhf(zg);
        float ov = 1.f / (1.f + expf(-zo));
        creg = fv * creg + iv * gv;
        float h = ov * tanhf(creg);
        f16 h16 = (f16)h;

        hbuf[(t & 1) * (BB * HH) + gb * HH + jbase + gj] = h16;
        if (t == TT - 1) {
            out[OUT_TAIL + gb * HH + jbase + gj] = h;
            out[OUT_TAIL + BB * HH + gb * HH + jbase + gj] = creg;
        }

        __syncthreads();   // per-wave vmcnt drain of h-writes before publish
        if (tid == 0) {
            __threadfence();  // writeback XCD L2 (covers all waves' h-writes)
            __hip_atomic_store(&flags[bid], (unsigned)(t + 1), __ATOMIC_RELEASE,
                               __HIP_MEMORY_SCOPE_AGENT);
        }
        // off the critical path: history write for the dense stage
        seq16[(size_t)t * (BB * HH) + gb * HH + jbase + gj] = h16;
    }
}

// ---------------------------------------------------------------------------
// Dense(32, tanh) via MFMA. Block = (b0, t-chunk of 64): 4 waves x 16 t-rows.
// A rows = seq16[t, b0, :] (fixed b0 => coalesced per-(b,t) output stores).
// ---------------------------------------------------------------------------
__global__ __launch_bounds__(256) void dense_mfma(
    const f16* __restrict__ seq16,    // [T,B,H]
    const float* __restrict__ dw,     // [H,DS]
    const float* __restrict__ db,     // [DS]
    float* __restrict__ out)          // [B,T,DS]
{
    __shared__ f16 dwlds[32 * 520];   // [col][k], stride 520

    const int tid = threadIdx.x;
    for (int idx = tid; idx < HH * DSZ; idx += 256) {
        int k = idx >> 5, n = idx & 31;
        dwlds[n * 520 + k] = (f16)dw[idx];
    }
    __syncthreads();

    const int wave = tid >> 6, lane = tid & 63;
    const int b0 = blockIdx.x & 63;
    const int t0 = (blockIdx.x >> 6) * 64 + wave * 16;
    const int kseg = (lane >> 4) * 8;
    const int col = lane & 15;

    const f16* ap = seq16 + ((size_t)(t0 + col) * BB + b0) * HH + kseg;

    f32x4 acc0 = {0.f, 0.f, 0.f, 0.f};
    f32x4 acc1 = {0.f, 0.f, 0.f, 0.f};
    #pragma unroll
    for (int ks = 0; ks < 16; ++ks) {
        f16x8 a  = *(const f16x8*)(ap + ks * 32);
        f16x8 w0 = *(const f16x8*)(dwlds + col * 520 + ks * 32 + kseg);
        f16x8 w1 = *(const f16x8*)(dwlds + (16 + col) * 520 + ks * 32 + kseg);
        acc0 = __builtin_amdgcn_mfma_f32_16x16x32_f16(a, w0, acc0, 0, 0, 0);
        acc1 = __builtin_amdgcn_mfma_f32_16x16x32_f16(a, w1, acc1, 0, 0, 0);
    }

    const float db0 = db[col], db1 = db[16 + col];
    #pragma unroll
    for (int r = 0; r < 4; ++r) {
        int t = t0 + (lane >> 4) * 4 + r;
        size_t base = (size_t)b0 * (TT * DSZ) + (size_t)t * DSZ;
        out[base + col]      = tanhf(acc0[r] + db0);
        out[base + 16 + col] = tanhf(acc1[r] + db1);
    }
}

extern "C" void kernel_launch(void* const* d_in, const int* in_sizes, int n_in,
                              void* d_out, int out_size, void* d_ws, size_t ws_size,
                              hipStream_t stream) {
    const float* x    = (const float*)d_in[0];
    const float* kern = (const float*)d_in[1];
    const float* rker = (const float*)d_in[2];
    const float* bias = (const float*)d_in[3];
    const float* dw   = (const float*)d_in[4];
    const float* db   = (const float*)d_in[5];
    float* out = (float*)d_out;

    f16* seq16 = (f16*)d_ws;                                   // 33,554,432 B
    f16* hbuf  = (f16*)((char*)d_ws + (size_t)33554432);       // 131,072 B
    unsigned int* flags =
        (unsigned int*)((char*)d_ws + 33554432 + 131072);      // 256 B

    lstm_persistent<<<NBLK, NTHR, 0, stream>>>(
        x, kern, rker, bias, seq16, hbuf, flags, out);
    dense_mfma<<<512, 256, 0, stream>>>(seq16, dw, db, out);
}

// Round 6
// 2979.802 us; speedup vs baseline: 16.9286x; 1.7751x over previous
//
#include <hip/hip_runtime.h>
#include <math.h>

// B=64, T=512, D=128, H=512, DS=32
#define BB 64
#define TT 512
#define DD 128
#define HH 512
#define DSZ 32
#define G4 2048
#define NBLK 64
#define NTHR 512
#define OUT_TAIL (BB * TT * DSZ)

typedef _Float16 f16;
typedef f16  f16x8 __attribute__((ext_vector_type(8)));
typedef f16  f16x4 __attribute__((ext_vector_type(4)));
typedef float f32x4 __attribute__((ext_vector_type(4)));

// ---- LLC-coherent (sc0 sc1) access helpers: no fences, no L2 flushes ----
__device__ __forceinline__ void flag_store_sc(unsigned* p, unsigned v) {
    asm volatile("global_store_dword %0, %1, off sc0 sc1" :: "v"(p), "v"(v) : "memory");
}
__device__ __forceinline__ unsigned flag_load_sc(const unsigned* p) {
    unsigned v;
    asm volatile("global_load_dword %0, %1, off sc0 sc1\n\ts_waitcnt vmcnt(0)"
                 : "=v"(v) : "v"(p) : "memory");
    return v;
}
__device__ __forceinline__ void h_store_sc(f16* p, f16 v) {
    union { f16 f; unsigned short u; } c; c.f = v;
    unsigned vv = c.u;
    asm volatile("global_store_short %0, %1, off sc0 sc1" :: "v"(p), "v"(vv) : "memory");
}

__device__ __forceinline__ float sigm(float x) {
    return __builtin_amdgcn_rcpf(1.f + __expf(-x));
}
__device__ __forceinline__ float tanh_fast(float x) {
    return 2.f * __builtin_amdgcn_rcpf(1.f + __expf(-2.f * x)) - 1.f;
}

// ---------------------------------------------------------------------------
// Pre-GEMM: xwT[t][gcol][b] (f16) = x[b,t,:] @ kern[:,gcol]   (bias NOT added)
// ---------------------------------------------------------------------------
__global__ __launch_bounds__(256) void xw_gemm(
    const float* __restrict__ x, const float* __restrict__ kern,
    f16* __restrict__ xwT)
{
    extern __shared__ f16 klds[];           // [512 cols][136]
    const int cc = blockIdx.x & 3;          // col chunk (512 cols)
    const int tg = blockIdx.x >> 2;         // t-group (4 t)
    const int tid = threadIdx.x;

    for (int idx = tid; idx < 512 * 128; idx += 256) {
        int k = idx >> 9, c = idx & 511;
        klds[c * 136 + k] = (f16)kern[(size_t)k * G4 + cc * 512 + c];
    }
    __syncthreads();

    const int wave = tid >> 6, lane = tid & 63;
    const int cidx = lane & 15;
    const int kseg = (lane >> 4) * 8;

    for (int t = tg * 4; t < tg * 4 + 4; ++t) {
        f16x8 Af[4][4];
        #pragma unroll
        for (int mt = 0; mt < 4; ++mt) {
            const float* xp = x + ((size_t)(mt * 16 + cidx) * TT + t) * DD + kseg;
            #pragma unroll
            for (int ks = 0; ks < 4; ++ks) {
                float4 a = *(const float4*)(xp + ks * 32);
                float4 b = *(const float4*)(xp + ks * 32 + 4);
                f16x8 f;
                f[0]=(f16)a.x; f[1]=(f16)a.y; f[2]=(f16)a.z; f[3]=(f16)a.w;
                f[4]=(f16)b.x; f[5]=(f16)b.y; f[6]=(f16)b.z; f[7]=(f16)b.w;
                Af[mt][ks] = f;
            }
        }
        for (int nt = 0; nt < 8; ++nt) {
            const int colc = (wave * 8 + nt) * 16 + cidx;
            f16x8 Bf[4];
            #pragma unroll
            for (int ks = 0; ks < 4; ++ks)
                Bf[ks] = *(const f16x8*)&klds[colc * 136 + ks * 32 + kseg];
            #pragma unroll
            for (int mt = 0; mt < 4; ++mt) {
                f32x4 a = {0.f, 0.f, 0.f, 0.f};
                #pragma unroll
                for (int ks = 0; ks < 4; ++ks)
                    a = __builtin_amdgcn_mfma_f32_16x16x32_f16(Af[mt][ks], Bf[ks], a, 0, 0, 0);
                f16x4 hv;
                #pragma unroll
                for (int r = 0; r < 4; ++r) hv[r] = (f16)a[r];
                const int gcol = cc * 512 + colc;
                const int brow = mt * 16 + (lane >> 4) * 4;
                *(f16x4*)(xwT + ((size_t)t * G4 + gcol) * BB + brow) = hv;
            }
        }
    }
}

// ---------------------------------------------------------------------------
// Persistent LSTM. Block bid owns units [bid*8, bid*8+8).
// Wave col mapping: c=lane&15, gate g=c>>2, unit j=bid*8+ntile*4+(c&3).
// Gates exchanged with 3x shfl_xor. Cross-block h/flags via sc0sc1. LDS: none.
// ---------------------------------------------------------------------------
template<bool XW>
__global__ __launch_bounds__(NTHR, 1) void lstm_persist(
    const float* __restrict__ x, const float* __restrict__ kern,
    const float* __restrict__ rker, const float* __restrict__ bias,
    const f16* __restrict__ xwT, f16* __restrict__ seq16,
    f16* __restrict__ hbuf, unsigned* __restrict__ flags,
    float* __restrict__ out)
{
    const int tid = threadIdx.x, bid = blockIdx.x;
    const int wave = tid >> 6, lane = tid & 63;
    const int mtile = wave & 3, ntile = wave >> 2;
    const int c  = lane & 15;
    const int g  = c >> 2;
    const int j  = bid * 8 + ntile * 4 + (c & 3);
    const int gcol = g * HH + j;
    const int kseg = (lane >> 4) * 8;
    const int brow = mtile * 16 + (lane >> 4) * 4;
    const int arow = mtile * 16 + c;

    // one-time: recurrent weight fragments -> VGPRs
    f16x8 wfrag[16];
    #pragma unroll
    for (int ks = 0; ks < 16; ++ks) {
        f16x8 w;
        #pragma unroll
        for (int jj = 0; jj < 8; ++jj)
            w[jj] = (f16)rker[(size_t)(ks * 32 + kseg + jj) * G4 + gcol];
        wfrag[ks] = w;
    }
    f16x8 kfrag[4];
    if (!XW) {
        #pragma unroll
        for (int ks = 0; ks < 4; ++ks) {
            f16x8 w;
            #pragma unroll
            for (int jj = 0; jj < 8; ++jj)
                w[jj] = (f16)kern[(size_t)(ks * 32 + kseg + jj) * G4 + gcol];
            kfrag[ks] = w;
        }
    }

    float bias4[4];
    #pragma unroll
    for (int g2 = 0; g2 < 4; ++g2) bias4[g2] = bias[g2 * HH + j];

    float creg[4] = {0.f, 0.f, 0.f, 0.f};
    const bool leader = (g == 0);

    for (int t = 0; t < TT; ++t) {
        // ---- acc init = x-projection (independent of recurrence) ----
        f32x4 acc;
        if (XW) {
            f16x4 xv = *(const f16x4*)(xwT + ((size_t)t * G4 + gcol) * BB + brow);
            acc[0] = (float)xv[0]; acc[1] = (float)xv[1];
            acc[2] = (float)xv[2]; acc[3] = (float)xv[3];
        } else {
            acc = (f32x4){0.f, 0.f, 0.f, 0.f};
            const float* xp = x + ((size_t)arow * TT + t) * DD + kseg;
            #pragma unroll
            for (int ks = 0; ks < 4; ++ks) {
                float4 a = *(const float4*)(xp + ks * 32);
                float4 b = *(const float4*)(xp + ks * 32 + 4);
                f16x8 xa;
                xa[0]=(f16)a.x; xa[1]=(f16)a.y; xa[2]=(f16)a.z; xa[3]=(f16)a.w;
                xa[4]=(f16)b.x; xa[5]=(f16)b.y; xa[6]=(f16)b.z; xa[7]=(f16)b.w;
                acc = __builtin_amdgcn_mfma_f32_16x16x32_f16(xa, kfrag[ks], acc, 0, 0, 0);
            }
        }

        if (t > 0) {
            // ---- wait for h(t-1): monotone >= poll (0xAA.. poison is negative) ----
            if (wave == 0) {
                const unsigned* fp = flags + (lane << 4);
                while ((int)flag_load_sc(fp) < t) {}
            }
            __syncthreads();
            // ---- 16 sc0sc1 b128 loads of h(t-1); "=&v" EARLY-CLOBBER is load-
            // bearing: without it LLVM may alloc outputs over %16 (dead-after-asm)
            // and the later loads read a clobbered address -> memory fault. ----
            const f16* hp = hbuf + ((t - 1) & 1) * (BB * HH) + (size_t)arow * HH + kseg;
            f16x8 h0,h1,h2,h3,h4v,h5,h6,h7,h8,h9,h10,h11,h12,h13,h14,h15;
            asm volatile(
                "global_load_dwordx4 %0, %16, off sc0 sc1\n\t"
                "global_load_dwordx4 %1, %16, off offset:64 sc0 sc1\n\t"
                "global_load_dwordx4 %2, %16, off offset:128 sc0 sc1\n\t"
                "global_load_dwordx4 %3, %16, off offset:192 sc0 sc1\n\t"
                "global_load_dwordx4 %4, %16, off offset:256 sc0 sc1\n\t"
                "global_load_dwordx4 %5, %16, off offset:320 sc0 sc1\n\t"
                "global_load_dwordx4 %6, %16, off offset:384 sc0 sc1\n\t"
                "global_load_dwordx4 %7, %16, off offset:448 sc0 sc1\n\t"
                "global_load_dwordx4 %8, %16, off offset:512 sc0 sc1\n\t"
                "global_load_dwordx4 %9, %16, off offset:576 sc0 sc1\n\t"
                "global_load_dwordx4 %10, %16, off offset:640 sc0 sc1\n\t"
                "global_load_dwordx4 %11, %16, off offset:704 sc0 sc1\n\t"
                "global_load_dwordx4 %12, %16, off offset:768 sc0 sc1\n\t"
                "global_load_dwordx4 %13, %16, off offset:832 sc0 sc1\n\t"
                "global_load_dwordx4 %14, %16, off offset:896 sc0 sc1\n\t"
                "global_load_dwordx4 %15, %16, off offset:960 sc0 sc1\n\t"
                "s_waitcnt vmcnt(0)"
                : "=&v"(h0),"=&v"(h1),"=&v"(h2),"=&v"(h3),"=&v"(h4v),"=&v"(h5),
                  "=&v"(h6),"=&v"(h7),"=&v"(h8),"=&v"(h9),"=&v"(h10),"=&v"(h11),
                  "=&v"(h12),"=&v"(h13),"=&v"(h14),"=&v"(h15)
                : "v"(hp) : "memory");
            acc = __builtin_amdgcn_mfma_f32_16x16x32_f16(h0,  wfrag[0],  acc, 0, 0, 0);
            acc = __builtin_amdgcn_mfma_f32_16x16x32_f16(h1,  wfrag[1],  acc, 0, 0, 0);
            acc = __builtin_amdgcn_mfma_f32_16x16x32_f16(h2,  wfrag[2],  acc, 0, 0, 0);
            acc = __builtin_amdgcn_mfma_f32_16x16x32_f16(h3,  wfrag[3],  acc, 0, 0, 0);
            acc = __builtin_amdgcn_mfma_f32_16x16x32_f16(h4v, wfrag[4],  acc, 0, 0, 0);
            acc = __builtin_amdgcn_mfma_f32_16x16x32_f16(h5,  wfrag[5],  acc, 0, 0, 0);
            acc = __builtin_amdgcn_mfma_f32_16x16x32_f16(h6,  wfrag[6],  acc, 0, 0, 0);
            acc = __builtin_amdgcn_mfma_f32_16x16x32_f16(h7,  wfrag[7],  acc, 0, 0, 0);
            acc = __builtin_amdgcn_mfma_f32_16x16x32_f16(h8,  wfrag[8],  acc, 0, 0, 0);
            acc = __builtin_amdgcn_mfma_f32_16x16x32_f16(h9,  wfrag[9],  acc, 0, 0, 0);
            acc = __builtin_amdgcn_mfma_f32_16x16x32_f16(h10, wfrag[10], acc, 0, 0, 0);
            acc = __builtin_amdgcn_mfma_f32_16x16x32_f16(h11, wfrag[11], acc, 0, 0, 0);
            acc = __builtin_amdgcn_mfma_f32_16x16x32_f16(h12, wfrag[12], acc, 0, 0, 0);
            acc = __builtin_amdgcn_mfma_f32_16x16x32_f16(h13, wfrag[13], acc, 0, 0, 0);
            acc = __builtin_amdgcn_mfma_f32_16x16x32_f16(h14, wfrag[14], acc, 0, 0, 0);
            acc = __builtin_amdgcn_mfma_f32_16x16x32_f16(h15, wfrag[15], acc, 0, 0, 0);
        }

        // ---- gates: 3 shfl_xor per row gathers all 4 gate z's ----
        float hv4[4];
        #pragma unroll
        for (int r = 0; r < 4; ++r) {
            float z0 = acc[r];
            float za = __shfl_xor(z0, 4);
            float zb = __shfl_xor(z0, 8);
            float zc = __shfl_xor(z0, 12);
            float s0 = z0, s1 = za, s2 = zb, s3 = zc;
            if (g & 1) { float u=s0; s0=s1; s1=u; u=s2; s2=s3; s3=u; }
            if (g & 2) { float u=s0; s0=s2; s2=u; u=s1; s1=s3; s3=u; }
            float iv = sigm(s0 + bias4[0]);
            float fv = sigm(s1 + bias4[1]);
            float gv = tanh_fast(s2 + bias4[2]);
            float ov = sigm(s3 + bias4[3]);
            creg[r] = fv * creg[r] + iv * gv;
            hv4[r] = ov * tanh_fast(creg[r]);
        }

        // ---- publish h(t): sc stores -> barrier (vmcnt drain) -> flag ----
        if (leader) {
            #pragma unroll
            for (int r = 0; r < 4; ++r)
                h_store_sc(hbuf + (t & 1) * (BB * HH) + (size_t)(brow + r) * HH + j,
                           (f16)hv4[r]);
        }
        __syncthreads();
        if (tid == 0) flag_store_sc(flags + (bid << 4), (unsigned)(t + 1));

        // ---- off critical path ----
        if (leader) {
            #pragma unroll
            for (int r = 0; r < 4; ++r)
                seq16[(size_t)t * (BB * HH) + (size_t)(brow + r) * HH + j] = (f16)hv4[r];
            if (t == TT - 1) {
                #pragma unroll
                for (int r = 0; r < 4; ++r) {
                    out[OUT_TAIL + (brow + r) * HH + j] = hv4[r];
                    out[OUT_TAIL + BB * HH + (brow + r) * HH + j] = creg[r];
                }
            }
        }
    }
}

// ---------------------------------------------------------------------------
// Dense(32, tanh) via MFMA.
// ---------------------------------------------------------------------------
__global__ __launch_bounds__(256) void dense_mfma(
    const f16* __restrict__ seq16, const float* __restrict__ dw,
    const float* __restrict__ db, float* __restrict__ out)
{
    __shared__ f16 dwlds[32 * 520];
    const int tid = threadIdx.x;
    for (int idx = tid; idx < HH * DSZ; idx += 256) {
        int k = idx >> 5, n = idx & 31;
        dwlds[n * 520 + k] = (f16)dw[idx];
    }
    __syncthreads();

    const int wave = tid >> 6, lane = tid & 63;
    const int b0 = blockIdx.x & 63;
    const int t0 = (blockIdx.x >> 6) * 64 + wave * 16;
    const int kseg = (lane >> 4) * 8;
    const int col = lane & 15;

    const f16* ap = seq16 + ((size_t)(t0 + col) * BB + b0) * HH + kseg;

    f32x4 acc0 = {0.f, 0.f, 0.f, 0.f};
    f32x4 acc1 = {0.f, 0.f, 0.f, 0.f};
    #pragma unroll
    for (int ks = 0; ks < 16; ++ks) {
        f16x8 a  = *(const f16x8*)(ap + ks * 32);
        f16x8 w0 = *(const f16x8*)(dwlds + col * 520 + ks * 32 + kseg);
        f16x8 w1 = *(const f16x8*)(dwlds + (16 + col) * 520 + ks * 32 + kseg);
        acc0 = __builtin_amdgcn_mfma_f32_16x16x32_f16(a, w0, acc0, 0, 0, 0);
        acc1 = __builtin_amdgcn_mfma_f32_16x16x32_f16(a, w1, acc1, 0, 0, 0);
    }

    const float db0 = db[col], db1 = db[16 + col];
    #pragma unroll
    for (int r = 0; r < 4; ++r) {
        int t = t0 + (lane >> 4) * 4 + r;
        size_t base = (size_t)b0 * (TT * DSZ) + (size_t)t * DSZ;
        out[base + col]      = tanhf(acc0[r] + db0);
        out[base + 16 + col] = tanhf(acc1[r] + db1);
    }
}

extern "C" void kernel_launch(void* const* d_in, const int* in_sizes, int n_in,
                              void* d_out, int out_size, void* d_ws, size_t ws_size,
                              hipStream_t stream) {
    const float* x    = (const float*)d_in[0];
    const float* kern = (const float*)d_in[1];
    const float* rker = (const float*)d_in[2];
    const float* bias = (const float*)d_in[3];
    const float* dw   = (const float*)d_in[4];
    const float* db   = (const float*)d_in[5];
    float* out = (float*)d_out;

    char* ws = (char*)d_ws;
    f16* seq16 = (f16*)ws;                                   // 33,554,432 B
    f16* hbuf  = (f16*)(ws + 33554432);                      //    131,072 B
    unsigned* flags = (unsigned*)(ws + 33554432 + 131072);   //      4,096 B
    f16* xwT   = (f16*)(ws + 33689600);                      // 134,217,728 B

    const bool use_xw = (ws_size >= 33689600ull + 134217728ull);

    if (use_xw) {
        hipFuncSetAttribute(reinterpret_cast<const void*>(xw_gemm),
                            hipFuncAttributeMaxDynamicSharedMemorySize, 139264);
        xw_gemm<<<512, 256, 139264, stream>>>(x, kern, xwT);
        lstm_persist<true><<<NBLK, NTHR, 0, stream>>>(
            x, kern, rker, bias, xwT, seq16, hbuf, flags, out);
    } else {
        lstm_persist<false><<<NBLK, NTHR, 0, stream>>>(
            x, kern, rker, bias, (const f16*)nullptr, seq16, hbuf, flags, out);
    }
    dense_mfma<<<512, 256, 0, stream>>>(seq16, dw, db, out);
}

// Round 7
// 2105.209 us; speedup vs baseline: 23.9615x; 1.4154x over previous
//
#include <hip/hip_runtime.h>
#include <math.h>

// B=64, T=512, D=128, H=512, DS=32
#define BB 64
#define TT 512
#define DD 128
#define HH 512
#define DSZ 32
#define G4 2048
#define NBLK 64
#define NTHR 256
#define BBHH (BB * HH)
#define OUT_TAIL (BB * TT * DSZ)

typedef _Float16 f16;
typedef f16  f16x8 __attribute__((ext_vector_type(8)));
typedef f16  f16x4 __attribute__((ext_vector_type(4)));
typedef float f32x4 __attribute__((ext_vector_type(4)));

// ---- LLC-coherent (sc0 sc1) helpers: no fences, no L2 flushes ----
__device__ __forceinline__ void flag_store_sc(unsigned* p, unsigned v) {
    asm volatile("global_store_dword %0, %1, off sc0 sc1" :: "v"(p), "v"(v) : "memory");
}
__device__ __forceinline__ unsigned flag_load_sc(const unsigned* p) {
    unsigned v;
    asm volatile("global_load_dword %0, %1, off sc0 sc1\n\ts_waitcnt vmcnt(0)"
                 : "=v"(v) : "v"(p) : "memory");
    return v;
}
__device__ __forceinline__ void h_store_sc(f16* p, f16 v) {
    union { f16 f; unsigned short u; } cv; cv.f = v;
    unsigned vv = cv.u;
    asm volatile("global_store_short %0, %1, off sc0 sc1" :: "v"(p), "v"(vv) : "memory");
}

__device__ __forceinline__ float sigm(float x) {
    return __builtin_amdgcn_rcpf(1.f + __expf(-x));
}
__device__ __forceinline__ float tanh_fast(float x) {
    return 2.f * __builtin_amdgcn_rcpf(1.f + __expf(-2.f * x)) - 1.f;
}

// ---------------------------------------------------------------------------
// Pre-GEMM: xwT[t][gcol][b] (f16) = x[b,t,:] @ kern[:,gcol]  (bias NOT added)
// ---------------------------------------------------------------------------
__global__ __launch_bounds__(256) void xw_gemm(
    const float* __restrict__ x, const float* __restrict__ kern,
    f16* __restrict__ xwT)
{
    extern __shared__ f16 klds[];           // [512 cols][136]
    const int cc = blockIdx.x & 3;
    const int tg = blockIdx.x >> 2;
    const int tid = threadIdx.x;

    for (int idx = tid; idx < 512 * 128; idx += 256) {
        int k = idx >> 9, c = idx & 511;
        klds[c * 136 + k] = (f16)kern[(size_t)k * G4 + cc * 512 + c];
    }
    __syncthreads();

    const int wave = tid >> 6, lane = tid & 63;
    const int cidx = lane & 15;
    const int kseg = (lane >> 4) * 8;

    for (int t = tg * 4; t < tg * 4 + 4; ++t) {
        f16x8 Af[4][4];
        #pragma unroll
        for (int mt = 0; mt < 4; ++mt) {
            const float* xp = x + ((size_t)(mt * 16 + cidx) * TT + t) * DD + kseg;
            #pragma unroll
            for (int ks = 0; ks < 4; ++ks) {
                float4 a = *(const float4*)(xp + ks * 32);
                float4 b = *(const float4*)(xp + ks * 32 + 4);
                f16x8 f;
                f[0]=(f16)a.x; f[1]=(f16)a.y; f[2]=(f16)a.z; f[3]=(f16)a.w;
                f[4]=(f16)b.x; f[5]=(f16)b.y; f[6]=(f16)b.z; f[7]=(f16)b.w;
                Af[mt][ks] = f;
            }
        }
        for (int nt = 0; nt < 8; ++nt) {
            const int colc = (wave * 8 + nt) * 16 + cidx;
            f16x8 Bf[4];
            #pragma unroll
            for (int ks = 0; ks < 4; ++ks)
                Bf[ks] = *(const f16x8*)&klds[colc * 136 + ks * 32 + kseg];
            #pragma unroll
            for (int mt = 0; mt < 4; ++mt) {
                f32x4 a = {0.f, 0.f, 0.f, 0.f};
                #pragma unroll
                for (int ks = 0; ks < 4; ++ks)
                    a = __builtin_amdgcn_mfma_f32_16x16x32_f16(Af[mt][ks], Bf[ks], a, 0, 0, 0);
                f16x4 hv;
                #pragma unroll
                for (int r = 0; r < 4; ++r) hv[r] = (f16)a[r];
                const int gcol = cc * 512 + colc;
                const int brow = mt * 16 + (lane >> 4) * 4;
                *(f16x4*)(xwT + ((size_t)t * G4 + gcol) * BB + brow) = hv;
            }
        }
    }
}

// ---------------------------------------------------------------------------
// Persistent LSTM: 64 blocks x 256 thr (4 waves = 4 batch m-tiles).
// Block col c in [0,32): unit u=c&7, gate=c>>3 (cols 0-15 gates i,f -> acc0;
// cols 16-31 gates g,o -> acc1). Each wave computes both n-halves over full
// K=512 -> no duplicate h loads. Per-wave independent flag polling; split
// loads pipelined across the second poll and first MFMA group.
// ---------------------------------------------------------------------------
template<bool XW>
__global__ __launch_bounds__(NTHR, 1) void lstm_persist(
    const float* __restrict__ x, const float* __restrict__ kern,
    const float* __restrict__ rker, const float* __restrict__ bias,
    const f16* __restrict__ xwT, f16* __restrict__ seq16,
    f16* __restrict__ hbuf, unsigned* __restrict__ flags,
    float* __restrict__ out)
{
    const int tid = threadIdx.x, bid = blockIdx.x;
    const int wave = tid >> 6, lane = tid & 63;   // wave = batch m-tile
    const int c = lane & 15;
    const int q = lane >> 4;
    const int kseg = q * 8;
    const int arow = wave * 16 + c;               // A-frag batch row
    const int brow = wave * 16 + q * 4;           // C-frag batch row base
    const int u0 = c & 7;
    const int g0 = c >> 3;                        // 0 or 1
    const int j0 = bid * 8 + u0;
    const int gcolA = g0 * HH + j0;               // acc0 column (gate i/f)
    const int gcolB = (2 + g0) * HH + j0;         // acc1 column (gate g/o)

    // ---- one-time: recurrent weight fragments -> VGPRs (128 VGPRs) ----
    f16x8 wfA[16], wfB[16];
    #pragma unroll
    for (int ks = 0; ks < 16; ++ks) {
        f16x8 wa, wb;
        #pragma unroll
        for (int jj = 0; jj < 8; ++jj) {
            int k = ks * 32 + kseg + jj;
            wa[jj] = (f16)rker[(size_t)k * G4 + gcolA];
            wb[jj] = (f16)rker[(size_t)k * G4 + gcolB];
        }
        wfA[ks] = wa; wfB[ks] = wb;
    }
    f16x8 kfA[4], kfB[4];
    if (!XW) {
        #pragma unroll
        for (int ks = 0; ks < 4; ++ks) {
            f16x8 wa, wb;
            #pragma unroll
            for (int jj = 0; jj < 8; ++jj) {
                int k = ks * 32 + kseg + jj;
                wa[jj] = (f16)kern[(size_t)k * G4 + gcolA];
                wb[jj] = (f16)kern[(size_t)k * G4 + gcolB];
            }
            kfA[ks] = wa; kfB[ks] = wb;
        }
    }

    float bias4[4];
    #pragma unroll
    for (int g = 0; g < 4; ++g) bias4[g] = bias[g * HH + bid * 8 + u0];
    float creg[4] = {0.f, 0.f, 0.f, 0.f};

    for (int t = 0; t < TT; ++t) {
        // ---- acc init = x-projection ----
        f32x4 acc0, acc1;
        if (XW) {
            f16x4 xa = *(const f16x4*)(xwT + ((size_t)t * G4 + gcolA) * BB + brow);
            f16x4 xb = *(const f16x4*)(xwT + ((size_t)t * G4 + gcolB) * BB + brow);
            #pragma unroll
            for (int r = 0; r < 4; ++r) { acc0[r] = (float)xa[r]; acc1[r] = (float)xb[r]; }
        } else {
            acc0 = (f32x4){0.f,0.f,0.f,0.f}; acc1 = (f32x4){0.f,0.f,0.f,0.f};
            const float* xp = x + ((size_t)arow * TT + t) * DD + kseg;
            #pragma unroll
            for (int ks = 0; ks < 4; ++ks) {
                float4 a = *(const float4*)(xp + ks * 32);
                float4 b = *(const float4*)(xp + ks * 32 + 4);
                f16x8 xa;
                xa[0]=(f16)a.x; xa[1]=(f16)a.y; xa[2]=(f16)a.z; xa[3]=(f16)a.w;
                xa[4]=(f16)b.x; xa[5]=(f16)b.y; xa[6]=(f16)b.z; xa[7]=(f16)b.w;
                acc0 = __builtin_amdgcn_mfma_f32_16x16x32_f16(xa, kfA[ks], acc0, 0, 0, 0);
                acc1 = __builtin_amdgcn_mfma_f32_16x16x32_f16(xa, kfB[ks], acc1, 0, 0, 0);
            }
        }

        if (t > 0) {
            const f16* hp = hbuf + ((t - 1) & 1) * BBHH + (size_t)arow * HH + kseg;
            // ---- poll producers 0..31 (per-wave, no barrier) ----
            {
                const unsigned* fp = flags + ((lane & 31) << 4);
                while ((int)flag_load_sc(fp) < t) {}
            }
            // ---- issue h-loads ks 0..7 (no wait; fly under next poll) ----
            f16x8 h0,h1,h2,h3,h4,h5,h6,h7;
            asm volatile(
                "global_load_dwordx4 %0, %8, off sc0 sc1\n\t"
                "global_load_dwordx4 %1, %8, off offset:64 sc0 sc1\n\t"
                "global_load_dwordx4 %2, %8, off offset:128 sc0 sc1\n\t"
                "global_load_dwordx4 %3, %8, off offset:192 sc0 sc1\n\t"
                "global_load_dwordx4 %4, %8, off offset:256 sc0 sc1\n\t"
                "global_load_dwordx4 %5, %8, off offset:320 sc0 sc1\n\t"
                "global_load_dwordx4 %6, %8, off offset:384 sc0 sc1\n\t"
                "global_load_dwordx4 %7, %8, off offset:448 sc0 sc1"
                : "=&v"(h0),"=&v"(h1),"=&v"(h2),"=&v"(h3),
                  "=&v"(h4),"=&v"(h5),"=&v"(h6),"=&v"(h7)
                : "v"(hp) : "memory");
            // ---- poll producers 32..63 (its vmcnt(0) also drains loads 0..7) ----
            {
                const unsigned* fp = flags + ((32 + (lane & 31)) << 4);
                while ((int)flag_load_sc(fp) < t) {}
            }
            // ---- issue h-loads ks 8..15; "+v" ties order groupA MFMAs after ----
            f16x8 h8,h9,h10,h11,h12,h13,h14,h15;
            asm volatile(
                "global_load_dwordx4 %0, %16, off offset:512 sc0 sc1\n\t"
                "global_load_dwordx4 %1, %16, off offset:576 sc0 sc1\n\t"
                "global_load_dwordx4 %2, %16, off offset:640 sc0 sc1\n\t"
                "global_load_dwordx4 %3, %16, off offset:704 sc0 sc1\n\t"
                "global_load_dwordx4 %4, %16, off offset:768 sc0 sc1\n\t"
                "global_load_dwordx4 %5, %16, off offset:832 sc0 sc1\n\t"
                "global_load_dwordx4 %6, %16, off offset:896 sc0 sc1\n\t"
                "global_load_dwordx4 %7, %16, off offset:960 sc0 sc1\n\t"
                "s_waitcnt vmcnt(8)"
                : "=&v"(h8),"=&v"(h9),"=&v"(h10),"=&v"(h11),
                  "=&v"(h12),"=&v"(h13),"=&v"(h14),"=&v"(h15),
                  "+v"(h0),"+v"(h1),"+v"(h2),"+v"(h3),
                  "+v"(h4),"+v"(h5),"+v"(h6),"+v"(h7)
                : "v"(hp) : "memory");
            __builtin_amdgcn_sched_barrier(0);
            // ---- MFMA ks 0..7 (overlaps loads 8..15 in flight) ----
            acc0 = __builtin_amdgcn_mfma_f32_16x16x32_f16(h0, wfA[0], acc0, 0, 0, 0);
            acc1 = __builtin_amdgcn_mfma_f32_16x16x32_f16(h0, wfB[0], acc1, 0, 0, 0);
            acc0 = __builtin_amdgcn_mfma_f32_16x16x32_f16(h1, wfA[1], acc0, 0, 0, 0);
            acc1 = __builtin_amdgcn_mfma_f32_16x16x32_f16(h1, wfB[1], acc1, 0, 0, 0);
            acc0 = __builtin_amdgcn_mfma_f32_16x16x32_f16(h2, wfA[2], acc0, 0, 0, 0);
            acc1 = __builtin_amdgcn_mfma_f32_16x16x32_f16(h2, wfB[2], acc1, 0, 0, 0);
            acc0 = __builtin_amdgcn_mfma_f32_16x16x32_f16(h3, wfA[3], acc0, 0, 0, 0);
            acc1 = __builtin_amdgcn_mfma_f32_16x16x32_f16(h3, wfB[3], acc1, 0, 0, 0);
            acc0 = __builtin_amdgcn_mfma_f32_16x16x32_f16(h4, wfA[4], acc0, 0, 0, 0);
            acc1 = __builtin_amdgcn_mfma_f32_16x16x32_f16(h4, wfB[4], acc1, 0, 0, 0);
            acc0 = __builtin_amdgcn_mfma_f32_16x16x32_f16(h5, wfA[5], acc0, 0, 0, 0);
            acc1 = __builtin_amdgcn_mfma_f32_16x16x32_f16(h5, wfB[5], acc1, 0, 0, 0);
            acc0 = __builtin_amdgcn_mfma_f32_16x16x32_f16(h6, wfA[6], acc0, 0, 0, 0);
            acc1 = __builtin_amdgcn_mfma_f32_16x16x32_f16(h6, wfB[6], acc1, 0, 0, 0);
            acc0 = __builtin_amdgcn_mfma_f32_16x16x32_f16(h7, wfA[7], acc0, 0, 0, 0);
            acc1 = __builtin_amdgcn_mfma_f32_16x16x32_f16(h7, wfB[7], acc1, 0, 0, 0);
            // ---- drain loads 8..15, then MFMA ks 8..15 ----
            asm volatile("s_waitcnt vmcnt(0)"
                : "+v"(h8),"+v"(h9),"+v"(h10),"+v"(h11),
                  "+v"(h12),"+v"(h13),"+v"(h14),"+v"(h15));
            __builtin_amdgcn_sched_barrier(0);
            acc0 = __builtin_amdgcn_mfma_f32_16x16x32_f16(h8,  wfA[8],  acc0, 0, 0, 0);
            acc1 = __builtin_amdgcn_mfma_f32_16x16x32_f16(h8,  wfB[8],  acc1, 0, 0, 0);
            acc0 = __builtin_amdgcn_mfma_f32_16x16x32_f16(h9,  wfA[9],  acc0, 0, 0, 0);
            acc1 = __builtin_amdgcn_mfma_f32_16x16x32_f16(h9,  wfB[9],  acc1, 0, 0, 0);
            acc0 = __builtin_amdgcn_mfma_f32_16x16x32_f16(h10, wfA[10], acc0, 0, 0, 0);
            acc1 = __builtin_amdgcn_mfma_f32_16x16x32_f16(h10, wfB[10], acc1, 0, 0, 0);
            acc0 = __builtin_amdgcn_mfma_f32_16x16x32_f16(h11, wfA[11], acc0, 0, 0, 0);
            acc1 = __builtin_amdgcn_mfma_f32_16x16x32_f16(h11, wfB[11], acc1, 0, 0, 0);
            acc0 = __builtin_amdgcn_mfma_f32_16x16x32_f16(h12, wfA[12], acc0, 0, 0, 0);
            acc1 = __builtin_amdgcn_mfma_f32_16x16x32_f16(h12, wfB[12], acc1, 0, 0, 0);
            acc0 = __builtin_amdgcn_mfma_f32_16x16x32_f16(h13, wfA[13], acc0, 0, 0, 0);
            acc1 = __builtin_amdgcn_mfma_f32_16x16x32_f16(h13, wfB[13], acc1, 0, 0, 0);
            acc0 = __builtin_amdgcn_mfma_f32_16x16x32_f16(h14, wfA[14], acc0, 0, 0, 0);
            acc1 = __builtin_amdgcn_mfma_f32_16x16x32_f16(h14, wfB[14], acc1, 0, 0, 0);
            acc0 = __builtin_amdgcn_mfma_f32_16x16x32_f16(h15, wfA[15], acc0, 0, 0, 0);
            acc1 = __builtin_amdgcn_mfma_f32_16x16x32_f16(h15, wfB[15], acc1, 0, 0, 0);
        }

        // ---- gate exchange: lane c (<8) pairs with c^8 (all lanes shuffle) ----
        float zf_[4], zo_[4];
        #pragma unroll
        for (int r = 0; r < 4; ++r) {
            zf_[r] = __shfl_xor(acc0[r], 8);
            zo_[r] = __shfl_xor(acc1[r], 8);
        }
        if (c < 8) {   // leader: unit j0, rows brow..brow+3
            #pragma unroll
            for (int r = 0; r < 4; ++r) {
                float iv = sigm(acc0[r] + bias4[0]);
                float fv = sigm(zf_[r]  + bias4[1]);
                float gv = tanh_fast(acc1[r] + bias4[2]);
                float ov = sigm(zo_[r]  + bias4[3]);
                creg[r] = fv * creg[r] + iv * gv;
                float h = ov * tanh_fast(creg[r]);
                f16 h16 = (f16)h;
                h_store_sc(hbuf + (t & 1) * BBHH + (size_t)(brow + r) * HH + j0, h16);
                seq16[(size_t)t * BBHH + (size_t)(brow + r) * HH + j0] = h16;
                if (t == TT - 1) {
                    out[OUT_TAIL + (brow + r) * HH + j0] = h;
                    out[OUT_TAIL + BB * HH + (brow + r) * HH + j0] = creg[r];
                }
            }
        }
        __syncthreads();   // implicit vmcnt(0): all waves' h stores ack'd at LLC
        if (tid == 0) flag_store_sc(flags + (bid << 4), (unsigned)(t + 1));
    }
}

// ---------------------------------------------------------------------------
// Dense(32, tanh) via MFMA.
// ---------------------------------------------------------------------------
__global__ __launch_bounds__(256) void dense_mfma(
    const f16* __restrict__ seq16, const float* __restrict__ dw,
    const float* __restrict__ db, float* __restrict__ out)
{
    __shared__ f16 dwlds[32 * 520];
    const int tid = threadIdx.x;
    for (int idx = tid; idx < HH * DSZ; idx += 256) {
        int k = idx >> 5, n = idx & 31;
        dwlds[n * 520 + k] = (f16)dw[idx];
    }
    __syncthreads();

    const int wave = tid >> 6, lane = tid & 63;
    const int b0 = blockIdx.x & 63;
    const int t0 = (blockIdx.x >> 6) * 64 + wave * 16;
    const int kseg = (lane >> 4) * 8;
    const int col = lane & 15;

    const f16* ap = seq16 + ((size_t)(t0 + col) * BB + b0) * HH + kseg;

    f32x4 acc0 = {0.f, 0.f, 0.f, 0.f};
    f32x4 acc1 = {0.f, 0.f, 0.f, 0.f};
    #pragma unroll
    for (int ks = 0; ks < 16; ++ks) {
        f16x8 a  = *(const f16x8*)(ap + ks * 32);
        f16x8 w0 = *(const f16x8*)(dwlds + col * 520 + ks * 32 + kseg);
        f16x8 w1 = *(const f16x8*)(dwlds + (16 + col) * 520 + ks * 32 + kseg);
        acc0 = __builtin_amdgcn_mfma_f32_16x16x32_f16(a, w0, acc0, 0, 0, 0);
        acc1 = __builtin_amdgcn_mfma_f32_16x16x32_f16(a, w1, acc1, 0, 0, 0);
    }

    const float db0 = db[col], db1 = db[16 + col];
    #pragma unroll
    for (int r = 0; r < 4; ++r) {
        int t = t0 + (lane >> 4) * 4 + r;
        size_t base = (size_t)b0 * (TT * DSZ) + (size_t)t * DSZ;
        out[base + col]      = tanhf(acc0[r] + db0);
        out[base + 16 + col] = tanhf(acc1[r] + db1);
    }
}

extern "C" void kernel_launch(void* const* d_in, const int* in_sizes, int n_in,
                              void* d_out, int out_size, void* d_ws, size_t ws_size,
                              hipStream_t stream) {
    const float* x    = (const float*)d_in[0];
    const float* kern = (const float*)d_in[1];
    const float* rker = (const float*)d_in[2];
    const float* bias = (const float*)d_in[3];
    const float* dw   = (const float*)d_in[4];
    const float* db   = (const float*)d_in[5];
    float* out = (float*)d_out;

    char* ws = (char*)d_ws;
    f16* seq16 = (f16*)ws;                                   // 33,554,432 B
    f16* hbuf  = (f16*)(ws + 33554432);                      //    131,072 B
    unsigned* flags = (unsigned*)(ws + 33554432 + 131072);   //      4,096 B
    f16* xwT   = (f16*)(ws + 33689600);                      // 134,217,728 B

    const bool use_xw = (ws_size >= 33689600ull + 134217728ull);

    if (use_xw) {
        hipFuncSetAttribute(reinterpret_cast<const void*>(xw_gemm),
                            hipFuncAttributeMaxDynamicSharedMemorySize, 139264);
        xw_gemm<<<512, 256, 139264, stream>>>(x, kern, xwT);
        lstm_persist<true><<<NBLK, NTHR, 0, stream>>>(
            x, kern, rker, bias, xwT, seq16, hbuf, flags, out);
    } else {
        lstm_persist<false><<<NBLK, NTHR, 0, stream>>>(
            x, kern, rker, bias, (const f16*)nullptr, seq16, hbuf, flags, out);
    }
    dense_mfma<<<512, 256, 0, stream>>>(seq16, dw, db, out);
}